// Round 2
// baseline (787.822 us; speedup 1.0000x reference)
//
#include <hip/hip_runtime.h>

#define NUM_SYM 50000
#define NUM_HERB 50000
#define N_NODES (NUM_SYM + NUM_HERB)
#define DIM 128

typedef float floatx4 __attribute__((ext_vector_type(4)));

__device__ __forceinline__ float bf2f(unsigned short u) {
    return __uint_as_float((unsigned)u << 16);
}
__device__ __forceinline__ unsigned short f2bf(float f) {
    unsigned u = __float_as_uint(f);
    unsigned r = (u + 0x7FFFu + ((u >> 16) & 1u)) >> 16;   // round-to-nearest-even
    return (unsigned short)r;
}

// ---------------- bf16 staging of the gather table ----------------
__global__ __launch_bounds__(256) void to_bf16(
    const float* __restrict__ sym, const float* __restrict__ herb,
    ushort* __restrict__ xbf)
{
    int i = blockIdx.x * 256 + threadIdx.x;          // float4 index
    const int n4 = N_NODES * DIM / 4;
    if (i >= n4) return;
    const int sym4 = NUM_SYM * DIM / 4;
    float4 v = (i < sym4) ? reinterpret_cast<const float4*>(sym)[i]
                          : reinterpret_cast<const float4*>(herb)[i - sym4];
    ushort4 o;
    o.x = f2bf(v.x); o.y = f2bf(v.y); o.z = f2bf(v.z); o.w = f2bf(v.w);
    reinterpret_cast<ushort4*>(xbf)[i] = o;
}

// ---------------- direct per-row counting sort (3 kernels) ----------------
// k1: per-row histogram via global atomics (edge-parallel, full occupancy)
__global__ __launch_bounds__(256) void hist_rows(
    const int* __restrict__ rows, int E, int* __restrict__ cnt)
{
    int stride = gridDim.x * 256;
    for (int e = blockIdx.x * 256 + threadIdx.x; e < E; e += stride)
        atomicAdd(&cnt[rows[e]], 1);
}

// k2: exclusive scan of 100000 counts -> rowptr + cursor. One 1024-thread
// block; thread t owns rows [t*100, t*100+100), int4-vectorized.
#define SEG 100
__global__ __launch_bounds__(1024) void scan_rows(
    const int* __restrict__ cnt, int* __restrict__ rowptr, int* __restrict__ cursor)
{
    __shared__ int s[1024];
    int t = threadIdx.x;
    int base = t * SEG;
    int sum = 0;
    if (base < N_NODES) {
        const int4* c4 = reinterpret_cast<const int4*>(cnt + base);
        #pragma unroll
        for (int i = 0; i < SEG / 4; ++i) {
            int4 v = c4[i];
            sum += v.x + v.y + v.z + v.w;
        }
    }
    s[t] = sum;
    __syncthreads();
    for (int o = 1; o < 1024; o <<= 1) {
        int x = (t >= o) ? s[t - o] : 0;
        __syncthreads();
        s[t] += x;
        __syncthreads();
    }
    int run = s[t] - sum;            // exclusive prefix of this segment
    if (base < N_NODES) {
        const int4* c4 = reinterpret_cast<const int4*>(cnt + base);
        int4* rp4 = reinterpret_cast<int4*>(rowptr + base);
        int4* cu4 = reinterpret_cast<int4*>(cursor + base);
        #pragma unroll
        for (int i = 0; i < SEG / 4; ++i) {
            int4 v = c4[i];
            int4 o4;
            o4.x = run;
            o4.y = o4.x + v.x;
            o4.z = o4.y + v.y;
            o4.w = o4.z + v.z;
            run  = o4.w + v.w;
            rp4[i] = o4;
            cu4[i] = o4;
        }
    }
}

// k3: scatter edges to final CSR position. Record (4B):
//     (val_bf16_lo15 << 17) | col    (vals > 0 so bf16 sign bit is 0)
__global__ __launch_bounds__(256) void scatter_csr(
    const int* __restrict__ rows, const int* __restrict__ cols,
    const float* __restrict__ vals, int E,
    int* __restrict__ cursor, int* __restrict__ csr)
{
    int stride = gridDim.x * 256;
    for (int e = blockIdx.x * 256 + threadIdx.x; e < E; e += stride) {
        int r = rows[e];
        int pos = atomicAdd(&cursor[r], 1);
        unsigned vb = (unsigned)f2bf(vals[e]);
        csr[pos] = (int)((vb << 17) | (unsigned)cols[e]);
    }
}

// ---------------- pull-mode SpMM over packed CSR, bf16 gathers ----------
// 2 rows per wave: lanes 0-31 -> row 2w, lanes 32-63 -> row 2w+1.
// 8x unroll: 8 independent 256B gathers in flight per half-wave.
__device__ __forceinline__ float unpack_val(int p) {
    return __uint_as_float(((unsigned)p >> 17) << 16);
}

template <bool FUSE_MEAN>
__global__ __launch_bounds__(256) void spmm_csr_bf16(
    const int* __restrict__ csr, const int* __restrict__ rowptr, int E,
    const ushort* __restrict__ xbf,
    const float* __restrict__ sym, const float* __restrict__ herb,
    const ushort* __restrict__ e1bf,
    void* __restrict__ outp)
{
    int wave = blockIdx.x * 4 + (threadIdx.x >> 6);
    int half = (threadIdx.x >> 5) & 1;
    int lane = threadIdx.x & 31;
    int r = wave * 2 + half;
    if (r >= N_NODES) return;

    int j   = rowptr[r];
    int end = (r + 1 < N_NODES) ? rowptr[r + 1] : E;

    float4 acc = make_float4(0.f, 0.f, 0.f, 0.f);
    for (; j + 7 < end; j += 8) {
        int p0 = __builtin_nontemporal_load(csr + j);
        int p1 = __builtin_nontemporal_load(csr + j + 1);
        int p2 = __builtin_nontemporal_load(csr + j + 2);
        int p3 = __builtin_nontemporal_load(csr + j + 3);
        int p4 = __builtin_nontemporal_load(csr + j + 4);
        int p5 = __builtin_nontemporal_load(csr + j + 5);
        int p6 = __builtin_nontemporal_load(csr + j + 6);
        int p7 = __builtin_nontemporal_load(csr + j + 7);
        ushort4 m0 = reinterpret_cast<const ushort4*>(xbf + (size_t)(p0 & 0x1FFFF) * DIM)[lane];
        ushort4 m1 = reinterpret_cast<const ushort4*>(xbf + (size_t)(p1 & 0x1FFFF) * DIM)[lane];
        ushort4 m2 = reinterpret_cast<const ushort4*>(xbf + (size_t)(p2 & 0x1FFFF) * DIM)[lane];
        ushort4 m3 = reinterpret_cast<const ushort4*>(xbf + (size_t)(p3 & 0x1FFFF) * DIM)[lane];
        ushort4 m4 = reinterpret_cast<const ushort4*>(xbf + (size_t)(p4 & 0x1FFFF) * DIM)[lane];
        ushort4 m5 = reinterpret_cast<const ushort4*>(xbf + (size_t)(p5 & 0x1FFFF) * DIM)[lane];
        ushort4 m6 = reinterpret_cast<const ushort4*>(xbf + (size_t)(p6 & 0x1FFFF) * DIM)[lane];
        ushort4 m7 = reinterpret_cast<const ushort4*>(xbf + (size_t)(p7 & 0x1FFFF) * DIM)[lane];
        float v0 = unpack_val(p0), v1 = unpack_val(p1);
        float v2 = unpack_val(p2), v3 = unpack_val(p3);
        float v4 = unpack_val(p4), v5 = unpack_val(p5);
        float v6 = unpack_val(p6), v7 = unpack_val(p7);
        acc.x += v0 * bf2f(m0.x) + v1 * bf2f(m1.x) + v2 * bf2f(m2.x) + v3 * bf2f(m3.x)
               + v4 * bf2f(m4.x) + v5 * bf2f(m5.x) + v6 * bf2f(m6.x) + v7 * bf2f(m7.x);
        acc.y += v0 * bf2f(m0.y) + v1 * bf2f(m1.y) + v2 * bf2f(m2.y) + v3 * bf2f(m3.y)
               + v4 * bf2f(m4.y) + v5 * bf2f(m5.y) + v6 * bf2f(m6.y) + v7 * bf2f(m7.y);
        acc.z += v0 * bf2f(m0.z) + v1 * bf2f(m1.z) + v2 * bf2f(m2.z) + v3 * bf2f(m3.z)
               + v4 * bf2f(m4.z) + v5 * bf2f(m5.z) + v6 * bf2f(m6.z) + v7 * bf2f(m7.z);
        acc.w += v0 * bf2f(m0.w) + v1 * bf2f(m1.w) + v2 * bf2f(m2.w) + v3 * bf2f(m3.w)
               + v4 * bf2f(m4.w) + v5 * bf2f(m5.w) + v6 * bf2f(m6.w) + v7 * bf2f(m7.w);
    }
    for (; j + 3 < end; j += 4) {
        int p0 = __builtin_nontemporal_load(csr + j);
        int p1 = __builtin_nontemporal_load(csr + j + 1);
        int p2 = __builtin_nontemporal_load(csr + j + 2);
        int p3 = __builtin_nontemporal_load(csr + j + 3);
        ushort4 m0 = reinterpret_cast<const ushort4*>(xbf + (size_t)(p0 & 0x1FFFF) * DIM)[lane];
        ushort4 m1 = reinterpret_cast<const ushort4*>(xbf + (size_t)(p1 & 0x1FFFF) * DIM)[lane];
        ushort4 m2 = reinterpret_cast<const ushort4*>(xbf + (size_t)(p2 & 0x1FFFF) * DIM)[lane];
        ushort4 m3 = reinterpret_cast<const ushort4*>(xbf + (size_t)(p3 & 0x1FFFF) * DIM)[lane];
        float v0 = unpack_val(p0), v1 = unpack_val(p1);
        float v2 = unpack_val(p2), v3 = unpack_val(p3);
        acc.x += v0 * bf2f(m0.x) + v1 * bf2f(m1.x) + v2 * bf2f(m2.x) + v3 * bf2f(m3.x);
        acc.y += v0 * bf2f(m0.y) + v1 * bf2f(m1.y) + v2 * bf2f(m2.y) + v3 * bf2f(m3.y);
        acc.z += v0 * bf2f(m0.z) + v1 * bf2f(m1.z) + v2 * bf2f(m2.z) + v3 * bf2f(m3.z);
        acc.w += v0 * bf2f(m0.w) + v1 * bf2f(m1.w) + v2 * bf2f(m2.w) + v3 * bf2f(m3.w);
    }
    for (; j < end; ++j) {
        int p0 = __builtin_nontemporal_load(csr + j);
        float v0 = unpack_val(p0);
        ushort4 m0 = reinterpret_cast<const ushort4*>(xbf + (size_t)(p0 & 0x1FFFF) * DIM)[lane];
        acc.x += v0 * bf2f(m0.x);
        acc.y += v0 * bf2f(m0.y);
        acc.z += v0 * bf2f(m0.z);
        acc.w += v0 * bf2f(m0.w);
    }

    if (FUSE_MEAN) {
        const float4* egorow = (r < NUM_SYM)
            ? reinterpret_cast<const float4*>(sym  + (size_t)r * DIM)
            : reinterpret_cast<const float4*>(herb + (size_t)(r - NUM_SYM) * DIM);
        float4 g = egorow[lane];
        ushort4 a = reinterpret_cast<const ushort4*>(e1bf + (size_t)r * DIM)[lane];
        const float s = 1.0f / 3.0f;
        floatx4 o;
        o.x = (g.x + bf2f(a.x) + acc.x) * s;
        o.y = (g.y + bf2f(a.y) + acc.y) * s;
        o.z = (g.z + bf2f(a.z) + acc.z) * s;
        o.w = (g.w + bf2f(a.w) + acc.w) * s;
        __builtin_nontemporal_store(o,
            reinterpret_cast<floatx4*>((float*)outp + (size_t)r * DIM) + lane);
    } else {
        ushort4 o;
        o.x = f2bf(acc.x); o.y = f2bf(acc.y); o.z = f2bf(acc.z); o.w = f2bf(acc.w);
        reinterpret_cast<ushort4*>((ushort*)outp + (size_t)r * DIM)[lane] = o;
    }
}

// ---------------- fallback (round-1 verified atomic path) ----------------
__global__ __launch_bounds__(256) void spmm_scatter(
    const int* __restrict__ rows, const int* __restrict__ cols,
    const float* __restrict__ vals, int n_edges,
    const float* __restrict__ xa, const float* __restrict__ xb,
    float* __restrict__ out)
{
    int gid = blockIdx.x * 256 + threadIdx.x;
    int edge = gid >> 5;
    if (edge >= n_edges) return;
    int sub = gid & 31;
    int c = cols[edge];
    int r = rows[edge];
    float v = vals[edge];
    const float* xrow = (c < NUM_SYM) ? (xa + (size_t)c * DIM)
                                      : (xb + (size_t)(c - NUM_SYM) * DIM);
    float4 m = reinterpret_cast<const float4*>(xrow)[sub];
    float* o = out + (size_t)r * DIM + (size_t)sub * 4;
    unsafeAtomicAdd(o + 0, v * m.x);
    unsafeAtomicAdd(o + 1, v * m.y);
    unsafeAtomicAdd(o + 2, v * m.z);
    unsafeAtomicAdd(o + 3, v * m.w);
}

__global__ __launch_bounds__(256) void finalize_mean(
    const float* __restrict__ sym, const float* __restrict__ herb,
    const float* __restrict__ e1, float* __restrict__ out)
{
    int i = blockIdx.x * 256 + threadIdx.x;
    const int n4 = N_NODES * DIM / 4;
    if (i >= n4) return;
    const int sym4 = NUM_SYM * DIM / 4;
    float4 e = (i < sym4) ? reinterpret_cast<const float4*>(sym)[i]
                          : reinterpret_cast<const float4*>(herb)[i - sym4];
    float4 a = reinterpret_cast<const float4*>(e1)[i];
    float4 b = reinterpret_cast<float4*>(out)[i];
    const float s = 1.0f / 3.0f;
    float4 r;
    r.x = (e.x + a.x + b.x) * s;
    r.y = (e.y + a.y + b.y) * s;
    r.z = (e.z + a.z + b.z) * s;
    r.w = (e.w + a.w + b.w) * s;
    reinterpret_cast<float4*>(out)[i] = r;
}

extern "C" void kernel_launch(void* const* d_in, const int* in_sizes, int n_in,
                              void* d_out, int out_size, void* d_ws, size_t ws_size,
                              hipStream_t stream) {
    const float* sym  = (const float*)d_in[0];
    const float* herb = (const float*)d_in[1];
    const int*   rows = (const int*)d_in[2];
    const int*   cols = (const int*)d_in[3];
    const float* vals = (const float*)d_in[4];
    const int E = in_sizes[2];
    float* out = (float*)d_out;

    // workspace layout:
    //   xbf [25.6MB]  (first 400KB aliased by cursor during sort — dead by to_bf16)
    //   csr [E*4]     (first 400KB aliased by cnt during hist/scan — dead by scatter)
    //   e1bf [25.6MB]
    //   rowptr [400KB]
    char* ws = (char*)d_ws;
    auto align256 = [](size_t x) { return (x + 255) & ~(size_t)255; };
    const size_t xbf_bytes   = (size_t)N_NODES * DIM * sizeof(ushort);   // 25.6 MB
    const size_t csr_off     = align256(xbf_bytes);
    const size_t e1_off      = align256(csr_off + (size_t)E * 4);
    const size_t rowptr_off  = align256(e1_off + xbf_bytes);
    const size_t required    = rowptr_off + (size_t)N_NODES * 4;

    if (ws_size < required || E >= (1 << 22)) {
        // fallback: verified round-1 atomic-scatter path (needs only 51.2MB e1)
        float* e1 = (float*)ws;
        const size_t e1_bytes = (size_t)N_NODES * DIM * sizeof(float);
        hipMemsetAsync(e1, 0, e1_bytes, stream);
        hipMemsetAsync(out, 0, e1_bytes, stream);
        const int spmm_blocks = (E * 32 + 255) / 256;
        spmm_scatter<<<spmm_blocks, 256, 0, stream>>>(rows, cols, vals, E, sym, herb, e1);
        spmm_scatter<<<spmm_blocks, 256, 0, stream>>>(rows, cols, vals, E,
                                                      e1, e1 + (size_t)NUM_SYM * DIM, out);
        const int n4 = N_NODES * DIM / 4;
        finalize_mean<<<(n4 + 255) / 256, 256, 0, stream>>>(sym, herb, e1, out);
        return;
    }

    ushort* xbf    = (ushort*)ws;
    int*    cursor = (int*)ws;                       // aliases xbf head (dead before to_bf16)
    int*    csr    = (int*)(ws + csr_off);
    int*    cnt    = (int*)(ws + csr_off);           // aliases csr head (dead before scatter)
    ushort* e1bf   = (ushort*)(ws + e1_off);
    int*    rowptr = (int*)(ws + rowptr_off);

    // --- direct per-row counting sort -> packed CSR ---
    hipMemsetAsync(cnt, 0, (size_t)N_NODES * 4, stream);
    hist_rows<<<2048, 256, 0, stream>>>(rows, E, cnt);
    scan_rows<<<1, 1024, 0, stream>>>(cnt, rowptr, cursor);
    scatter_csr<<<2048, 256, 0, stream>>>(rows, cols, vals, E, cursor, csr);

    // --- bf16 gather table (after scatter: overwrites the cursor alias) ---
    const int n4 = N_NODES * DIM / 4;
    to_bf16<<<(n4 + 255) / 256, 256, 0, stream>>>(sym, herb, xbf);

    // --- 2 propagation layers (pull over CSR) ---
    const int blocks = (N_NODES / 2 + 3) / 4;   // 2 rows/wave, 4 waves/block
    spmm_csr_bf16<false><<<blocks, 256, 0, stream>>>(csr, rowptr, E, xbf,
                                                     nullptr, nullptr, nullptr, e1bf);
    spmm_csr_bf16<true><<<blocks, 256, 0, stream>>>(csr, rowptr, E, e1bf,
                                                    sym, herb, e1bf, out);
}

// Round 3
// 462.291 us; speedup vs baseline: 1.7042x; 1.7042x over previous
//
#include <hip/hip_runtime.h>

#define NUM_SYM 50000
#define NUM_HERB 50000
#define N_NODES (NUM_SYM + NUM_HERB)
#define DIM 128
#define NB_BUCKETS ((N_NODES + 255) / 256)   // 391 coarse buckets of 256 rows
#define CHUNK 8192                           // edges per block in bucket passes
#define PAD 16                               // ints per bucket counter (64B line)

typedef float floatx4 __attribute__((ext_vector_type(4)));

__device__ __forceinline__ float bf2f(unsigned short u) {
    return __uint_as_float((unsigned)u << 16);
}
__device__ __forceinline__ unsigned short f2bf(float f) {
    unsigned u = __float_as_uint(f);
    unsigned r = (u + 0x7FFFu + ((u >> 16) & 1u)) >> 16;   // round-to-nearest-even
    return (unsigned short)r;
}

// ---------------- bf16 staging of the gather table ----------------
__global__ __launch_bounds__(256) void to_bf16(
    const float* __restrict__ sym, const float* __restrict__ herb,
    ushort* __restrict__ xbf)
{
    int i = blockIdx.x * 256 + threadIdx.x;          // float4 index
    const int n4 = N_NODES * DIM / 4;
    if (i >= n4) return;
    const int sym4 = NUM_SYM * DIM / 4;
    float4 v = (i < sym4) ? reinterpret_cast<const float4*>(sym)[i]
                          : reinterpret_cast<const float4*>(herb)[i - sym4];
    ushort4 o;
    o.x = f2bf(v.x); o.y = f2bf(v.y); o.z = f2bf(v.z); o.w = f2bf(v.w);
    reinterpret_cast<ushort4*>(xbf)[i] = o;
}

// ---------------- two-level bucket sort (row-sorted CSR) ------------
// Coarse buckets of 256 rows keep every scatter destination window small
// (32KB in k4 -> L1/L2-resident, ~1.3x write amp in k3 via per-block
// contiguous reservations). 1024-thread blocks: 391 blocks x 16 waves
// = 76% device occupancy (the round-0 version ran the same structure at
// 256/512 threads = 19-38% occupancy and was ~10x off its traffic floor).

// k1: coarse histogram, LDS-privatized
__global__ __launch_bounds__(1024) void hist_buckets(
    const int* __restrict__ rows, int E, int* __restrict__ bucket_cnt)
{
    __shared__ int h[NB_BUCKETS];
    for (int i = threadIdx.x; i < NB_BUCKETS; i += 1024) h[i] = 0;
    __syncthreads();
    int start = blockIdx.x * CHUNK;
    int end   = min(start + CHUNK, E);
    for (int e = start + threadIdx.x; e < end; e += 1024)
        atomicAdd(&h[rows[e] >> 8], 1);
    __syncthreads();
    for (int i = threadIdx.x; i < NB_BUCKETS; i += 1024)
        if (h[i]) atomicAdd(&bucket_cnt[i * PAD], h[i]);
}

// k2: scan 391 bucket counts -> offsets [0..NB_BUCKETS] + padded cursor
__global__ __launch_bounds__(512) void scan_buckets(
    const int* __restrict__ cnt, int* __restrict__ off, int* __restrict__ cursor)
{
    __shared__ int s[512];
    int t = threadIdx.x;
    int v = (t < NB_BUCKETS) ? cnt[t * PAD] : 0;
    s[t] = v;
    __syncthreads();
    for (int o = 1; o < 512; o <<= 1) {
        int x = (t >= o) ? s[t - o] : 0;
        __syncthreads();
        s[t] += x;
        __syncthreads();
    }
    if (t < NB_BUCKETS) { off[t] = s[t] - v; cursor[t * PAD] = s[t] - v; }
    if (t == NB_BUCKETS - 1) off[NB_BUCKETS] = s[t];
}

// k3: scatter edges into coarse buckets; one global atomicAdd per
// (block,bucket) reserves a contiguous range.
// Record: x = (row_low8 << 17) | col,  y = fp32 val bits.
__global__ __launch_bounds__(1024) void scatter_buckets(
    const int* __restrict__ rows, const int* __restrict__ cols,
    const float* __restrict__ vals, int E,
    int* __restrict__ cursor, int2* __restrict__ bucketed)
{
    __shared__ int lh[NB_BUCKETS];
    __shared__ int lbase[NB_BUCKETS];
    for (int i = threadIdx.x; i < NB_BUCKETS; i += 1024) lh[i] = 0;
    __syncthreads();
    int start = blockIdx.x * CHUNK;
    int end   = min(start + CHUNK, E);
    for (int e = start + threadIdx.x; e < end; e += 1024)
        atomicAdd(&lh[rows[e] >> 8], 1);
    __syncthreads();
    for (int i = threadIdx.x; i < NB_BUCKETS; i += 1024) {
        int c = lh[i];
        lbase[i] = c ? atomicAdd(&cursor[i * PAD], c) : 0;
        lh[i] = 0;                               // reuse as local cursor
    }
    __syncthreads();
    for (int e = start + threadIdx.x; e < end; e += 1024) {
        int r = rows[e];
        int key = r >> 8;
        int pos = lbase[key] + atomicAdd(&lh[key], 1);
        bucketed[pos] = make_int2(((r & 255) << 17) | cols[e],
                                  __float_as_int(vals[e]));
    }
}

// k4: one 1024-thread block per bucket -> row-sorted packed CSR + rowptr.
// CSR record (4B): (val_bf16_lo15 << 17) | col   (vals>0 so sign bit is 0)
__global__ __launch_bounds__(1024) void bucket_to_csr(
    const int2* __restrict__ bucketed, const int* __restrict__ off,
    int* __restrict__ csr, int* __restrict__ rowptr)
{
    __shared__ int h[256];
    int b = blockIdx.x, t = threadIdx.x;
    int s0 = off[b], s1 = off[b + 1];
    if (t < 256) h[t] = 0;
    __syncthreads();
    for (int j = s0 + t; j < s1; j += 1024)
        atomicAdd(&h[(unsigned)bucketed[j].x >> 17], 1);
    __syncthreads();
    int v = (t < 256) ? h[t] : 0;
    for (int o = 1; o < 256; o <<= 1) {          // inclusive scan (256 bins)
        int x = (t < 256 && t >= o) ? h[t - o] : 0;
        __syncthreads();
        if (t < 256) h[t] += x;
        __syncthreads();
    }
    if (t < 256) {
        int r = b * 256 + t;
        if (r < N_NODES) rowptr[r] = s0 + (h[t] - v);
    }
    __syncthreads();
    if (t < 256) h[t] -= v;                      // exclusive -> local cursor
    __syncthreads();
    for (int j = s0 + t; j < s1; j += 1024) {
        int2 rec = bucketed[j];
        int key = (unsigned)rec.x >> 17;
        int pos = s0 + atomicAdd(&h[key], 1);
        unsigned vb = (unsigned)f2bf(__int_as_float(rec.y));   // sign 0, 15 bits
        csr[pos] = (int)((vb << 17) | ((unsigned)rec.x & 0x1FFFFu));
    }
}

// ---------------- pull-mode SpMM over packed CSR, bf16 gathers ----------
// 2 rows per wave: lanes 0-31 -> row 2w, lanes 32-63 -> row 2w+1.
// 8x unroll: 8 independent 256B gathers in flight per half-wave.
__device__ __forceinline__ float unpack_val(int p) {
    return __uint_as_float(((unsigned)p >> 17) << 16);
}

template <bool FUSE_MEAN>
__global__ __launch_bounds__(256) void spmm_csr_bf16(
    const int* __restrict__ csr, const int* __restrict__ rowptr, int E,
    const ushort* __restrict__ xbf,
    const float* __restrict__ sym, const float* __restrict__ herb,
    const ushort* __restrict__ e1bf,
    void* __restrict__ outp)
{
    int wave = blockIdx.x * 4 + (threadIdx.x >> 6);
    int half = (threadIdx.x >> 5) & 1;
    int lane = threadIdx.x & 31;
    int r = wave * 2 + half;
    if (r >= N_NODES) return;

    int j   = rowptr[r];
    int end = (r + 1 < N_NODES) ? rowptr[r + 1] : E;

    float4 acc = make_float4(0.f, 0.f, 0.f, 0.f);
    for (; j + 7 < end; j += 8) {
        int p0 = __builtin_nontemporal_load(csr + j);
        int p1 = __builtin_nontemporal_load(csr + j + 1);
        int p2 = __builtin_nontemporal_load(csr + j + 2);
        int p3 = __builtin_nontemporal_load(csr + j + 3);
        int p4 = __builtin_nontemporal_load(csr + j + 4);
        int p5 = __builtin_nontemporal_load(csr + j + 5);
        int p6 = __builtin_nontemporal_load(csr + j + 6);
        int p7 = __builtin_nontemporal_load(csr + j + 7);
        ushort4 m0 = reinterpret_cast<const ushort4*>(xbf + (size_t)(p0 & 0x1FFFF) * DIM)[lane];
        ushort4 m1 = reinterpret_cast<const ushort4*>(xbf + (size_t)(p1 & 0x1FFFF) * DIM)[lane];
        ushort4 m2 = reinterpret_cast<const ushort4*>(xbf + (size_t)(p2 & 0x1FFFF) * DIM)[lane];
        ushort4 m3 = reinterpret_cast<const ushort4*>(xbf + (size_t)(p3 & 0x1FFFF) * DIM)[lane];
        ushort4 m4 = reinterpret_cast<const ushort4*>(xbf + (size_t)(p4 & 0x1FFFF) * DIM)[lane];
        ushort4 m5 = reinterpret_cast<const ushort4*>(xbf + (size_t)(p5 & 0x1FFFF) * DIM)[lane];
        ushort4 m6 = reinterpret_cast<const ushort4*>(xbf + (size_t)(p6 & 0x1FFFF) * DIM)[lane];
        ushort4 m7 = reinterpret_cast<const ushort4*>(xbf + (size_t)(p7 & 0x1FFFF) * DIM)[lane];
        float v0 = unpack_val(p0), v1 = unpack_val(p1);
        float v2 = unpack_val(p2), v3 = unpack_val(p3);
        float v4 = unpack_val(p4), v5 = unpack_val(p5);
        float v6 = unpack_val(p6), v7 = unpack_val(p7);
        acc.x += v0 * bf2f(m0.x) + v1 * bf2f(m1.x) + v2 * bf2f(m2.x) + v3 * bf2f(m3.x)
               + v4 * bf2f(m4.x) + v5 * bf2f(m5.x) + v6 * bf2f(m6.x) + v7 * bf2f(m7.x);
        acc.y += v0 * bf2f(m0.y) + v1 * bf2f(m1.y) + v2 * bf2f(m2.y) + v3 * bf2f(m3.y)
               + v4 * bf2f(m4.y) + v5 * bf2f(m5.y) + v6 * bf2f(m6.y) + v7 * bf2f(m7.y);
        acc.z += v0 * bf2f(m0.z) + v1 * bf2f(m1.z) + v2 * bf2f(m2.z) + v3 * bf2f(m3.z)
               + v4 * bf2f(m4.z) + v5 * bf2f(m5.z) + v6 * bf2f(m6.z) + v7 * bf2f(m7.z);
        acc.w += v0 * bf2f(m0.w) + v1 * bf2f(m1.w) + v2 * bf2f(m2.w) + v3 * bf2f(m3.w)
               + v4 * bf2f(m4.w) + v5 * bf2f(m5.w) + v6 * bf2f(m6.w) + v7 * bf2f(m7.w);
    }
    for (; j + 3 < end; j += 4) {
        int p0 = __builtin_nontemporal_load(csr + j);
        int p1 = __builtin_nontemporal_load(csr + j + 1);
        int p2 = __builtin_nontemporal_load(csr + j + 2);
        int p3 = __builtin_nontemporal_load(csr + j + 3);
        ushort4 m0 = reinterpret_cast<const ushort4*>(xbf + (size_t)(p0 & 0x1FFFF) * DIM)[lane];
        ushort4 m1 = reinterpret_cast<const ushort4*>(xbf + (size_t)(p1 & 0x1FFFF) * DIM)[lane];
        ushort4 m2 = reinterpret_cast<const ushort4*>(xbf + (size_t)(p2 & 0x1FFFF) * DIM)[lane];
        ushort4 m3 = reinterpret_cast<const ushort4*>(xbf + (size_t)(p3 & 0x1FFFF) * DIM)[lane];
        float v0 = unpack_val(p0), v1 = unpack_val(p1);
        float v2 = unpack_val(p2), v3 = unpack_val(p3);
        acc.x += v0 * bf2f(m0.x) + v1 * bf2f(m1.x) + v2 * bf2f(m2.x) + v3 * bf2f(m3.x);
        acc.y += v0 * bf2f(m0.y) + v1 * bf2f(m1.y) + v2 * bf2f(m2.y) + v3 * bf2f(m3.y);
        acc.z += v0 * bf2f(m0.z) + v1 * bf2f(m1.z) + v2 * bf2f(m2.z) + v3 * bf2f(m3.z);
        acc.w += v0 * bf2f(m0.w) + v1 * bf2f(m1.w) + v2 * bf2f(m2.w) + v3 * bf2f(m3.w);
    }
    for (; j < end; ++j) {
        int p0 = __builtin_nontemporal_load(csr + j);
        float v0 = unpack_val(p0);
        ushort4 m0 = reinterpret_cast<const ushort4*>(xbf + (size_t)(p0 & 0x1FFFF) * DIM)[lane];
        acc.x += v0 * bf2f(m0.x);
        acc.y += v0 * bf2f(m0.y);
        acc.z += v0 * bf2f(m0.z);
        acc.w += v0 * bf2f(m0.w);
    }

    if (FUSE_MEAN) {
        const float4* egorow = (r < NUM_SYM)
            ? reinterpret_cast<const float4*>(sym  + (size_t)r * DIM)
            : reinterpret_cast<const float4*>(herb + (size_t)(r - NUM_SYM) * DIM);
        float4 g = egorow[lane];
        ushort4 a = reinterpret_cast<const ushort4*>(e1bf + (size_t)r * DIM)[lane];
        const float s = 1.0f / 3.0f;
        floatx4 o;
        o.x = (g.x + bf2f(a.x) + acc.x) * s;
        o.y = (g.y + bf2f(a.y) + acc.y) * s;
        o.z = (g.z + bf2f(a.z) + acc.z) * s;
        o.w = (g.w + bf2f(a.w) + acc.w) * s;
        __builtin_nontemporal_store(o,
            reinterpret_cast<floatx4*>((float*)outp + (size_t)r * DIM) + lane);
    } else {
        ushort4 o;
        o.x = f2bf(acc.x); o.y = f2bf(acc.y); o.z = f2bf(acc.z); o.w = f2bf(acc.w);
        reinterpret_cast<ushort4*>((ushort*)outp + (size_t)r * DIM)[lane] = o;
    }
}

// ---------------- fallback (round-1 verified atomic path) ----------------
__global__ __launch_bounds__(256) void spmm_scatter(
    const int* __restrict__ rows, const int* __restrict__ cols,
    const float* __restrict__ vals, int n_edges,
    const float* __restrict__ xa, const float* __restrict__ xb,
    float* __restrict__ out)
{
    int gid = blockIdx.x * 256 + threadIdx.x;
    int edge = gid >> 5;
    if (edge >= n_edges) return;
    int sub = gid & 31;
    int c = cols[edge];
    int r = rows[edge];
    float v = vals[edge];
    const float* xrow = (c < NUM_SYM) ? (xa + (size_t)c * DIM)
                                      : (xb + (size_t)(c - NUM_SYM) * DIM);
    float4 m = reinterpret_cast<const float4*>(xrow)[sub];
    float* o = out + (size_t)r * DIM + (size_t)sub * 4;
    unsafeAtomicAdd(o + 0, v * m.x);
    unsafeAtomicAdd(o + 1, v * m.y);
    unsafeAtomicAdd(o + 2, v * m.z);
    unsafeAtomicAdd(o + 3, v * m.w);
}

__global__ __launch_bounds__(256) void finalize_mean(
    const float* __restrict__ sym, const float* __restrict__ herb,
    const float* __restrict__ e1, float* __restrict__ out)
{
    int i = blockIdx.x * 256 + threadIdx.x;
    const int n4 = N_NODES * DIM / 4;
    if (i >= n4) return;
    const int sym4 = NUM_SYM * DIM / 4;
    float4 e = (i < sym4) ? reinterpret_cast<const float4*>(sym)[i]
                          : reinterpret_cast<const float4*>(herb)[i - sym4];
    float4 a = reinterpret_cast<const float4*>(e1)[i];
    float4 b = reinterpret_cast<float4*>(out)[i];
    const float s = 1.0f / 3.0f;
    float4 r;
    r.x = (e.x + a.x + b.x) * s;
    r.y = (e.y + a.y + b.y) * s;
    r.z = (e.z + a.z + b.z) * s;
    r.w = (e.w + a.w + b.w) * s;
    reinterpret_cast<float4*>(out)[i] = r;
}

extern "C" void kernel_launch(void* const* d_in, const int* in_sizes, int n_in,
                              void* d_out, int out_size, void* d_ws, size_t ws_size,
                              hipStream_t stream) {
    const float* sym  = (const float*)d_in[0];
    const float* herb = (const float*)d_in[1];
    const int*   rows = (const int*)d_in[2];
    const int*   cols = (const int*)d_in[3];
    const float* vals = (const float*)d_in[4];
    const int E = in_sizes[2];
    float* out = (float*)d_out;

    // workspace layout:
    //   xbf [25.6MB] | csr [E*4] | bucketed [E*8] (aliased by e1bf after k4) |
    //   rowptr [400KB] | bcnt [padded] | boff | bcur [padded]
    char* ws = (char*)d_ws;
    auto align256 = [](size_t x) { return (x + 255) & ~(size_t)255; };
    const size_t xbf_bytes   = (size_t)N_NODES * DIM * sizeof(ushort);   // 25.6 MB
    const size_t csr_off     = align256(xbf_bytes);
    const size_t buck_off    = align256(csr_off + (size_t)E * 4);
    const size_t buck_bytes  = (size_t)E * 8 > xbf_bytes ? (size_t)E * 8 : xbf_bytes;
    const size_t rowptr_off  = align256(buck_off + buck_bytes);
    const size_t bcnt_off    = align256(rowptr_off + (size_t)N_NODES * 4);
    const size_t boff_off    = align256(bcnt_off + (size_t)NB_BUCKETS * PAD * 4);
    const size_t bcur_off    = align256(boff_off + (size_t)(NB_BUCKETS + 1) * 4);
    const size_t required    = bcur_off + (size_t)NB_BUCKETS * PAD * 4;

    if (ws_size < required || E >= (1 << 22)) {
        // fallback: verified round-1 atomic-scatter path (needs only 51.2MB e1)
        float* e1 = (float*)ws;
        const size_t e1_bytes = (size_t)N_NODES * DIM * sizeof(float);
        hipMemsetAsync(e1, 0, e1_bytes, stream);
        hipMemsetAsync(out, 0, e1_bytes, stream);
        const int spmm_blocks = (E * 32 + 255) / 256;
        spmm_scatter<<<spmm_blocks, 256, 0, stream>>>(rows, cols, vals, E, sym, herb, e1);
        spmm_scatter<<<spmm_blocks, 256, 0, stream>>>(rows, cols, vals, E,
                                                      e1, e1 + (size_t)NUM_SYM * DIM, out);
        const int n4 = N_NODES * DIM / 4;
        finalize_mean<<<(n4 + 255) / 256, 256, 0, stream>>>(sym, herb, e1, out);
        return;
    }

    ushort* xbf      = (ushort*)ws;
    int*    csr      = (int*)(ws + csr_off);
    int2*   bucketed = (int2*)(ws + buck_off);
    ushort* e1bf     = (ushort*)(ws + buck_off);   // aliases bucketed (dead after k4)
    int*    rowptr   = (int*)(ws + rowptr_off);
    int*    bcnt     = (int*)(ws + bcnt_off);
    int*    boff     = (int*)(ws + boff_off);
    int*    bcur     = (int*)(ws + bcur_off);

    // --- build row-sorted packed CSR via two-level bucket sort ---
    hipMemsetAsync(bcnt, 0, (size_t)NB_BUCKETS * PAD * 4, stream);
    const int EB = (E + CHUNK - 1) / CHUNK;
    hist_buckets<<<EB, 1024, 0, stream>>>(rows, E, bcnt);
    scan_buckets<<<1, 512, 0, stream>>>(bcnt, boff, bcur);
    scatter_buckets<<<EB, 1024, 0, stream>>>(rows, cols, vals, E, bcur, bucketed);
    bucket_to_csr<<<NB_BUCKETS, 1024, 0, stream>>>(bucketed, boff, csr, rowptr);

    // --- bf16 gather table ---
    const int n4 = N_NODES * DIM / 4;
    to_bf16<<<(n4 + 255) / 256, 256, 0, stream>>>(sym, herb, xbf);

    // --- 2 propagation layers (pull over CSR) ---
    const int blocks = (N_NODES / 2 + 3) / 4;   // 2 rows/wave, 4 waves/block
    spmm_csr_bf16<false><<<blocks, 256, 0, stream>>>(csr, rowptr, E, xbf,
                                                     nullptr, nullptr, nullptr, e1bf);
    spmm_csr_bf16<true><<<blocks, 256, 0, stream>>>(csr, rowptr, E, e1bf,
                                                    sym, herb, e1bf, out);
}

// Round 4
// 452.269 us; speedup vs baseline: 1.7419x; 1.0222x over previous
//
#include <hip/hip_runtime.h>

#define NUM_SYM 50000
#define NUM_HERB 50000
#define N_NODES (NUM_SYM + NUM_HERB)
#define DIM 128
#define NB_BUCKETS ((N_NODES + 255) / 256)   // 391 coarse buckets of 256 rows
#define CHUNK 4096                           // edges per block in bucket passes
#define PAD 16                               // ints per bucket counter (64B line)

typedef float floatx4 __attribute__((ext_vector_type(4)));

__device__ __forceinline__ float bf2f(unsigned short u) {
    return __uint_as_float((unsigned)u << 16);
}
__device__ __forceinline__ unsigned short f2bf(float f) {
    unsigned u = __float_as_uint(f);
    unsigned r = (u + 0x7FFFu + ((u >> 16) & 1u)) >> 16;   // round-to-nearest-even
    return (unsigned short)r;
}

// ---------------- bf16 staging of the gather table ----------------
__global__ __launch_bounds__(256) void to_bf16(
    const float* __restrict__ sym, const float* __restrict__ herb,
    ushort* __restrict__ xbf)
{
    int i = blockIdx.x * 256 + threadIdx.x;          // float4 index
    const int n4 = N_NODES * DIM / 4;
    if (i >= n4) return;
    const int sym4 = NUM_SYM * DIM / 4;
    float4 v = (i < sym4) ? reinterpret_cast<const float4*>(sym)[i]
                          : reinterpret_cast<const float4*>(herb)[i - sym4];
    ushort4 o;
    o.x = f2bf(v.x); o.y = f2bf(v.y); o.z = f2bf(v.z); o.w = f2bf(v.w);
    reinterpret_cast<ushort4*>(xbf)[i] = o;
}

// ---------------- two-level bucket sort (row-sorted CSR) ------------
// Coarse buckets of 256 rows keep every scatter destination window small.
// CHUNK=4096 -> 782 blocks (~3/CU) for the edge-parallel passes.

// k1: coarse histogram, LDS-privatized
__global__ __launch_bounds__(1024) void hist_buckets(
    const int* __restrict__ rows, int E, int* __restrict__ bucket_cnt)
{
    __shared__ int h[NB_BUCKETS];
    for (int i = threadIdx.x; i < NB_BUCKETS; i += 1024) h[i] = 0;
    __syncthreads();
    int start = blockIdx.x * CHUNK;
    int end   = min(start + CHUNK, E);
    for (int e = start + threadIdx.x; e < end; e += 1024)
        atomicAdd(&h[rows[e] >> 8], 1);
    __syncthreads();
    for (int i = threadIdx.x; i < NB_BUCKETS; i += 1024)
        if (h[i]) atomicAdd(&bucket_cnt[i * PAD], h[i]);
}

// k2: scan 391 bucket counts -> offsets [0..NB_BUCKETS] + padded cursor
__global__ __launch_bounds__(512) void scan_buckets(
    const int* __restrict__ cnt, int* __restrict__ off, int* __restrict__ cursor)
{
    __shared__ int s[512];
    int t = threadIdx.x;
    int v = (t < NB_BUCKETS) ? cnt[t * PAD] : 0;
    s[t] = v;
    __syncthreads();
    for (int o = 1; o < 512; o <<= 1) {
        int x = (t >= o) ? s[t - o] : 0;
        __syncthreads();
        s[t] += x;
        __syncthreads();
    }
    if (t < NB_BUCKETS) { off[t] = s[t] - v; cursor[t * PAD] = s[t] - v; }
    if (t == NB_BUCKETS - 1) off[NB_BUCKETS] = s[t];
}

// k3: scatter edges into coarse buckets; one global atomicAdd per
// (block,bucket) reserves a contiguous range.
// Record: x = (row_low8 << 17) | col,  y = fp32 val bits.
__global__ __launch_bounds__(1024) void scatter_buckets(
    const int* __restrict__ rows, const int* __restrict__ cols,
    const float* __restrict__ vals, int E,
    int* __restrict__ cursor, int2* __restrict__ bucketed)
{
    __shared__ int lh[NB_BUCKETS];
    __shared__ int lbase[NB_BUCKETS];
    for (int i = threadIdx.x; i < NB_BUCKETS; i += 1024) lh[i] = 0;
    __syncthreads();
    int start = blockIdx.x * CHUNK;
    int end   = min(start + CHUNK, E);
    for (int e = start + threadIdx.x; e < end; e += 1024)
        atomicAdd(&lh[rows[e] >> 8], 1);
    __syncthreads();
    for (int i = threadIdx.x; i < NB_BUCKETS; i += 1024) {
        int c = lh[i];
        lbase[i] = c ? atomicAdd(&cursor[i * PAD], c) : 0;
        lh[i] = 0;                               // reuse as local cursor
    }
    __syncthreads();
    for (int e = start + threadIdx.x; e < end; e += 1024) {
        int r = rows[e];
        int key = r >> 8;
        int pos = lbase[key] + atomicAdd(&lh[key], 1);
        bucketed[pos] = make_int2(((r & 255) << 17) | cols[e],
                                  __float_as_int(vals[e]));
    }
}

// k4: one 1024-thread block per bucket -> CSR sorted by (row, col_block).
// Bin key = (row_low8 << 4) | (col >> 13): 4096 bins. Within each row,
// edges come out ordered by 8K-node col-blocks, so during the spmm all
// waves sweep the gather table in loosely-synchronized phases and the
// instantaneous working set (~2-6MB) fits per-XCD L2.
// CSR record (4B): (val_bf16_lo15 << 17) | col   (vals>0 so sign bit is 0)
__global__ __launch_bounds__(1024) void bucket_to_csr(
    const int2* __restrict__ bucketed, const int* __restrict__ off,
    int* __restrict__ csr, int* __restrict__ rowptr)
{
    __shared__ int h[4096];
    __shared__ int s[1024];
    int b = blockIdx.x, t = threadIdx.x;
    int s0 = off[b], s1 = off[b + 1];
    #pragma unroll
    for (int i = 0; i < 4; ++i) h[t + i * 1024] = 0;
    __syncthreads();
    for (int j = s0 + t; j < s1; j += 1024) {
        unsigned x = (unsigned)bucketed[j].x;
        int bin = (int)(((x >> 17) << 4) | ((x & 0x1FFFFu) >> 13));
        atomicAdd(&h[bin], 1);
    }
    __syncthreads();
    // exclusive scan of 4096 bins; thread t owns bins [4t, 4t+4)
    int base = t * 4;
    int a0 = h[base], a1 = h[base + 1], a2 = h[base + 2], a3 = h[base + 3];
    int sum = a0 + a1 + a2 + a3;
    s[t] = sum;
    __syncthreads();
    for (int o = 1; o < 1024; o <<= 1) {
        int x = (t >= o) ? s[t - o] : 0;
        __syncthreads();
        s[t] += x;
        __syncthreads();
    }
    int excl = s[t] - sum;
    h[base]     = excl;
    h[base + 1] = excl + a0;
    h[base + 2] = excl + a0 + a1;
    h[base + 3] = excl + a0 + a1 + a2;
    __syncthreads();
    if (t < 256) {
        int r = b * 256 + t;
        if (r < N_NODES) rowptr[r] = s0 + h[t * 16];   // row start = bin (r,0)
    }
    __syncthreads();
    for (int j = s0 + t; j < s1; j += 1024) {
        int2 rec = bucketed[j];
        unsigned x = (unsigned)rec.x;
        int bin = (int)(((x >> 17) << 4) | ((x & 0x1FFFFu) >> 13));
        int pos = s0 + atomicAdd(&h[bin], 1);
        unsigned vb = (unsigned)f2bf(__int_as_float(rec.y));   // sign 0, 15 bits
        csr[pos] = (int)((vb << 17) | (x & 0x1FFFFu));
    }
}

// ---------------- pull-mode SpMM over packed CSR, bf16 gathers ----------
// 2 rows per wave: lanes 0-31 -> row 2w, lanes 32-63 -> row 2w+1.
// 8x unroll: 8 independent 256B gathers in flight per half-wave.
// Plain (cached) csr loads: each 64B line serves 16 records of the same
// lane -> nt hint caused ~2x csr refetch in round 3.
__device__ __forceinline__ float unpack_val(int p) {
    return __uint_as_float(((unsigned)p >> 17) << 16);
}

template <bool FUSE_MEAN>
__global__ __launch_bounds__(256) void spmm_csr_bf16(
    const int* __restrict__ csr, const int* __restrict__ rowptr, int E,
    const ushort* __restrict__ xbf,
    const float* __restrict__ sym, const float* __restrict__ herb,
    const ushort* __restrict__ e1bf,
    void* __restrict__ outp)
{
    int wave = blockIdx.x * 4 + (threadIdx.x >> 6);
    int half = (threadIdx.x >> 5) & 1;
    int lane = threadIdx.x & 31;
    int r = wave * 2 + half;
    if (r >= N_NODES) return;

    int j   = rowptr[r];
    int end = (r + 1 < N_NODES) ? rowptr[r + 1] : E;

    float4 acc = make_float4(0.f, 0.f, 0.f, 0.f);
    for (; j + 7 < end; j += 8) {
        int p0 = csr[j], p1 = csr[j + 1], p2 = csr[j + 2], p3 = csr[j + 3];
        int p4 = csr[j + 4], p5 = csr[j + 5], p6 = csr[j + 6], p7 = csr[j + 7];
        ushort4 m0 = reinterpret_cast<const ushort4*>(xbf + (size_t)(p0 & 0x1FFFF) * DIM)[lane];
        ushort4 m1 = reinterpret_cast<const ushort4*>(xbf + (size_t)(p1 & 0x1FFFF) * DIM)[lane];
        ushort4 m2 = reinterpret_cast<const ushort4*>(xbf + (size_t)(p2 & 0x1FFFF) * DIM)[lane];
        ushort4 m3 = reinterpret_cast<const ushort4*>(xbf + (size_t)(p3 & 0x1FFFF) * DIM)[lane];
        ushort4 m4 = reinterpret_cast<const ushort4*>(xbf + (size_t)(p4 & 0x1FFFF) * DIM)[lane];
        ushort4 m5 = reinterpret_cast<const ushort4*>(xbf + (size_t)(p5 & 0x1FFFF) * DIM)[lane];
        ushort4 m6 = reinterpret_cast<const ushort4*>(xbf + (size_t)(p6 & 0x1FFFF) * DIM)[lane];
        ushort4 m7 = reinterpret_cast<const ushort4*>(xbf + (size_t)(p7 & 0x1FFFF) * DIM)[lane];
        float v0 = unpack_val(p0), v1 = unpack_val(p1);
        float v2 = unpack_val(p2), v3 = unpack_val(p3);
        float v4 = unpack_val(p4), v5 = unpack_val(p5);
        float v6 = unpack_val(p6), v7 = unpack_val(p7);
        acc.x += v0 * bf2f(m0.x) + v1 * bf2f(m1.x) + v2 * bf2f(m2.x) + v3 * bf2f(m3.x)
               + v4 * bf2f(m4.x) + v5 * bf2f(m5.x) + v6 * bf2f(m6.x) + v7 * bf2f(m7.x);
        acc.y += v0 * bf2f(m0.y) + v1 * bf2f(m1.y) + v2 * bf2f(m2.y) + v3 * bf2f(m3.y)
               + v4 * bf2f(m4.y) + v5 * bf2f(m5.y) + v6 * bf2f(m6.y) + v7 * bf2f(m7.y);
        acc.z += v0 * bf2f(m0.z) + v1 * bf2f(m1.z) + v2 * bf2f(m2.z) + v3 * bf2f(m3.z)
               + v4 * bf2f(m4.z) + v5 * bf2f(m5.z) + v6 * bf2f(m6.z) + v7 * bf2f(m7.z);
        acc.w += v0 * bf2f(m0.w) + v1 * bf2f(m1.w) + v2 * bf2f(m2.w) + v3 * bf2f(m3.w)
               + v4 * bf2f(m4.w) + v5 * bf2f(m5.w) + v6 * bf2f(m6.w) + v7 * bf2f(m7.w);
    }
    for (; j + 3 < end; j += 4) {
        int p0 = csr[j], p1 = csr[j + 1], p2 = csr[j + 2], p3 = csr[j + 3];
        ushort4 m0 = reinterpret_cast<const ushort4*>(xbf + (size_t)(p0 & 0x1FFFF) * DIM)[lane];
        ushort4 m1 = reinterpret_cast<const ushort4*>(xbf + (size_t)(p1 & 0x1FFFF) * DIM)[lane];
        ushort4 m2 = reinterpret_cast<const ushort4*>(xbf + (size_t)(p2 & 0x1FFFF) * DIM)[lane];
        ushort4 m3 = reinterpret_cast<const ushort4*>(xbf + (size_t)(p3 & 0x1FFFF) * DIM)[lane];
        float v0 = unpack_val(p0), v1 = unpack_val(p1);
        float v2 = unpack_val(p2), v3 = unpack_val(p3);
        acc.x += v0 * bf2f(m0.x) + v1 * bf2f(m1.x) + v2 * bf2f(m2.x) + v3 * bf2f(m3.x);
        acc.y += v0 * bf2f(m0.y) + v1 * bf2f(m1.y) + v2 * bf2f(m2.y) + v3 * bf2f(m3.y);
        acc.z += v0 * bf2f(m0.z) + v1 * bf2f(m1.z) + v2 * bf2f(m2.z) + v3 * bf2f(m3.z);
        acc.w += v0 * bf2f(m0.w) + v1 * bf2f(m1.w) + v2 * bf2f(m2.w) + v3 * bf2f(m3.w);
    }
    for (; j < end; ++j) {
        int p0 = csr[j];
        float v0 = unpack_val(p0);
        ushort4 m0 = reinterpret_cast<const ushort4*>(xbf + (size_t)(p0 & 0x1FFFF) * DIM)[lane];
        acc.x += v0 * bf2f(m0.x);
        acc.y += v0 * bf2f(m0.y);
        acc.z += v0 * bf2f(m0.z);
        acc.w += v0 * bf2f(m0.w);
    }

    if (FUSE_MEAN) {
        const float4* egorow = (r < NUM_SYM)
            ? reinterpret_cast<const float4*>(sym  + (size_t)r * DIM)
            : reinterpret_cast<const float4*>(herb + (size_t)(r - NUM_SYM) * DIM);
        float4 g = egorow[lane];
        ushort4 a = reinterpret_cast<const ushort4*>(e1bf + (size_t)r * DIM)[lane];
        const float s = 1.0f / 3.0f;
        floatx4 o;
        o.x = (g.x + bf2f(a.x) + acc.x) * s;
        o.y = (g.y + bf2f(a.y) + acc.y) * s;
        o.z = (g.z + bf2f(a.z) + acc.z) * s;
        o.w = (g.w + bf2f(a.w) + acc.w) * s;
        __builtin_nontemporal_store(o,
            reinterpret_cast<floatx4*>((float*)outp + (size_t)r * DIM) + lane);
    } else {
        ushort4 o;
        o.x = f2bf(acc.x); o.y = f2bf(acc.y); o.z = f2bf(acc.z); o.w = f2bf(acc.w);
        reinterpret_cast<ushort4*>((ushort*)outp + (size_t)r * DIM)[lane] = o;
    }
}

// ---------------- fallback (round-1 verified atomic path) ----------------
__global__ __launch_bounds__(256) void spmm_scatter(
    const int* __restrict__ rows, const int* __restrict__ cols,
    const float* __restrict__ vals, int n_edges,
    const float* __restrict__ xa, const float* __restrict__ xb,
    float* __restrict__ out)
{
    int gid = blockIdx.x * 256 + threadIdx.x;
    int edge = gid >> 5;
    if (edge >= n_edges) return;
    int sub = gid & 31;
    int c = cols[edge];
    int r = rows[edge];
    float v = vals[edge];
    const float* xrow = (c < NUM_SYM) ? (xa + (size_t)c * DIM)
                                      : (xb + (size_t)(c - NUM_SYM) * DIM);
    float4 m = reinterpret_cast<const float4*>(xrow)[sub];
    float* o = out + (size_t)r * DIM + (size_t)sub * 4;
    unsafeAtomicAdd(o + 0, v * m.x);
    unsafeAtomicAdd(o + 1, v * m.y);
    unsafeAtomicAdd(o + 2, v * m.z);
    unsafeAtomicAdd(o + 3, v * m.w);
}

__global__ __launch_bounds__(256) void finalize_mean(
    const float* __restrict__ sym, const float* __restrict__ herb,
    const float* __restrict__ e1, float* __restrict__ out)
{
    int i = blockIdx.x * 256 + threadIdx.x;
    const int n4 = N_NODES * DIM / 4;
    if (i >= n4) return;
    const int sym4 = NUM_SYM * DIM / 4;
    float4 e = (i < sym4) ? reinterpret_cast<const float4*>(sym)[i]
                          : reinterpret_cast<const float4*>(herb)[i - sym4];
    float4 a = reinterpret_cast<const float4*>(e1)[i];
    float4 b = reinterpret_cast<float4*>(out)[i];
    const float s = 1.0f / 3.0f;
    float4 r;
    r.x = (e.x + a.x + b.x) * s;
    r.y = (e.y + a.y + b.y) * s;
    r.z = (e.z + a.z + b.z) * s;
    r.w = (e.w + a.w + b.w) * s;
    reinterpret_cast<float4*>(out)[i] = r;
}

extern "C" void kernel_launch(void* const* d_in, const int* in_sizes, int n_in,
                              void* d_out, int out_size, void* d_ws, size_t ws_size,
                              hipStream_t stream) {
    const float* sym  = (const float*)d_in[0];
    const float* herb = (const float*)d_in[1];
    const int*   rows = (const int*)d_in[2];
    const int*   cols = (const int*)d_in[3];
    const float* vals = (const float*)d_in[4];
    const int E = in_sizes[2];
    float* out = (float*)d_out;

    // workspace layout:
    //   xbf [25.6MB] | csr [E*4] | bucketed [E*8] (aliased by e1bf after k4) |
    //   rowptr [400KB] | bcnt [padded] | boff | bcur [padded]
    char* ws = (char*)d_ws;
    auto align256 = [](size_t x) { return (x + 255) & ~(size_t)255; };
    const size_t xbf_bytes   = (size_t)N_NODES * DIM * sizeof(ushort);   // 25.6 MB
    const size_t csr_off     = align256(xbf_bytes);
    const size_t buck_off    = align256(csr_off + (size_t)E * 4);
    const size_t buck_bytes  = (size_t)E * 8 > xbf_bytes ? (size_t)E * 8 : xbf_bytes;
    const size_t rowptr_off  = align256(buck_off + buck_bytes);
    const size_t bcnt_off    = align256(rowptr_off + (size_t)N_NODES * 4);
    const size_t boff_off    = align256(bcnt_off + (size_t)NB_BUCKETS * PAD * 4);
    const size_t bcur_off    = align256(boff_off + (size_t)(NB_BUCKETS + 1) * 4);
    const size_t required    = bcur_off + (size_t)NB_BUCKETS * PAD * 4;

    if (ws_size < required || E >= (1 << 22)) {
        // fallback: verified round-1 atomic-scatter path (needs only 51.2MB e1)
        float* e1 = (float*)ws;
        const size_t e1_bytes = (size_t)N_NODES * DIM * sizeof(float);
        hipMemsetAsync(e1, 0, e1_bytes, stream);
        hipMemsetAsync(out, 0, e1_bytes, stream);
        const int spmm_blocks = (E * 32 + 255) / 256;
        spmm_scatter<<<spmm_blocks, 256, 0, stream>>>(rows, cols, vals, E, sym, herb, e1);
        spmm_scatter<<<spmm_blocks, 256, 0, stream>>>(rows, cols, vals, E,
                                                      e1, e1 + (size_t)NUM_SYM * DIM, out);
        const int n4 = N_NODES * DIM / 4;
        finalize_mean<<<(n4 + 255) / 256, 256, 0, stream>>>(sym, herb, e1, out);
        return;
    }

    ushort* xbf      = (ushort*)ws;
    int*    csr      = (int*)(ws + csr_off);
    int2*   bucketed = (int2*)(ws + buck_off);
    ushort* e1bf     = (ushort*)(ws + buck_off);   // aliases bucketed (dead after k4)
    int*    rowptr   = (int*)(ws + rowptr_off);
    int*    bcnt     = (int*)(ws + bcnt_off);
    int*    boff     = (int*)(ws + boff_off);
    int*    bcur     = (int*)(ws + bcur_off);

    // --- build (row, col-block)-sorted packed CSR via two-level bucket sort ---
    hipMemsetAsync(bcnt, 0, (size_t)NB_BUCKETS * PAD * 4, stream);
    const int EB = (E + CHUNK - 1) / CHUNK;
    hist_buckets<<<EB, 1024, 0, stream>>>(rows, E, bcnt);
    scan_buckets<<<1, 512, 0, stream>>>(bcnt, boff, bcur);
    scatter_buckets<<<EB, 1024, 0, stream>>>(rows, cols, vals, E, bcur, bucketed);
    bucket_to_csr<<<NB_BUCKETS, 1024, 0, stream>>>(bucketed, boff, csr, rowptr);

    // --- bf16 gather table ---
    const int n4 = N_NODES * DIM / 4;
    to_bf16<<<(n4 + 255) / 256, 256, 0, stream>>>(sym, herb, xbf);

    // --- 2 propagation layers (pull over CSR) ---
    const int blocks = (N_NODES / 2 + 3) / 4;   // 2 rows/wave, 4 waves/block
    spmm_csr_bf16<false><<<blocks, 256, 0, stream>>>(csr, rowptr, E, xbf,
                                                     nullptr, nullptr, nullptr, e1bf);
    spmm_csr_bf16<true><<<blocks, 256, 0, stream>>>(csr, rowptr, E, e1bf,
                                                    sym, herb, e1bf, out);
}